// Round 2
// baseline (282.178 us; speedup 1.0000x reference)
//
#include <hip/hip_runtime.h>
#include <hip/hip_bf16.h>

#define N_NODES 10000
#define N_EDGES 160000
#define IN_CH   128
#define OUT_CH  64
#define HEADS   5
#define HO      320   // HEADS*OUT_CH

typedef __bf16 bf16;
typedef __bf16 bf16x8 __attribute__((ext_vector_type(8)));
typedef float  f32x4  __attribute__((ext_vector_type(4)));

// ---------------- CSR build ----------------

__global__ void zero_kernel(int* __restrict__ p, int n) {
    int i = blockIdx.x * blockDim.x + threadIdx.x;
    if (i < n) p[i] = 0;
}

__global__ void hist_kernel(const int* __restrict__ dst, int* __restrict__ counts, int e) {
    int i = blockIdx.x * blockDim.x + threadIdx.x;
    if (i < e) atomicAdd(&counts[dst[i]], 1);
}

__global__ __launch_bounds__(1024) void scan_kernel(const int* __restrict__ counts,
                                                    int* __restrict__ row_ptr,
                                                    int* __restrict__ cursor, int n) {
    __shared__ int ls[1024];
    const int C = 10;                       // ceil(10000/1024)
    int t = threadIdx.x;
    int base = t * C;
    int local[C];
    int s = 0;
    #pragma unroll
    for (int i = 0; i < C; i++) {
        int idx = base + i;
        int c = (idx < n) ? counts[idx] : 0;
        local[i] = c; s += c;
    }
    ls[t] = s;
    __syncthreads();
    for (int off = 1; off < 1024; off <<= 1) {
        int v_ = (t >= off) ? ls[t - off] : 0;
        __syncthreads();
        ls[t] += v_;
        __syncthreads();
    }
    int ex = (t == 0) ? 0 : ls[t - 1];
    #pragma unroll
    for (int i = 0; i < C; i++) {
        int idx = base + i;
        if (idx < n) { row_ptr[idx] = ex; cursor[idx] = ex; ex += local[i]; }
    }
    if (t == 0) row_ptr[n] = ls[1023];
}

__global__ void scatter_kernel(const int* __restrict__ src, const int* __restrict__ dst,
                               int* __restrict__ cursor, int* __restrict__ csr_src, int e) {
    int i = blockIdx.x * blockDim.x + threadIdx.x;
    if (i < e) {
        int d = dst[i];
        int pos = atomicAdd(&cursor[d], 1);
        csr_src[pos] = src[i];
    }
}

// ---------------- fused QKV+skip GEMM (MFMA bf16, f32 in/out) ----------------
// A [M,K] f32 row-major; weights [K,width] f32 row-major; converted to bf16
// in-register for MFMA (one RNE rounding; tolerance 7.8e-2 >> rounding err).
// grid.y = 16 col-groups of 64: g 0-4 -> Q, 5-9 -> K, 10-14 -> V, 15 -> skip.
// Block = 4 waves, 64 rows x 64 cols.
template<int K>
__global__ __launch_bounds__(256) void gemm_qkvs(
    const float* __restrict__ A, int M,
    const float* __restrict__ Wq, const float* __restrict__ Wk,
    const float* __restrict__ Wv, const float* __restrict__ Ws,
    const float* __restrict__ Bq, const float* __restrict__ Bk,
    const float* __restrict__ Bv, const float* __restrict__ Bs,
    float* __restrict__ outq, float* __restrict__ outk,
    float* __restrict__ outv, float* __restrict__ outs)
{
    int lane = threadIdx.x & 63;
    int wv   = threadIdx.x >> 6;
    int row0 = blockIdx.x * 64;
    int g    = blockIdx.y;
    int mi   = g / 5;                       // 0..3  (g=15 -> 3)
    const float* W  = (mi == 0) ? Wq : (mi == 1) ? Wk : (mi == 2) ? Wv : Ws;
    const float* Bi = (mi == 0) ? Bq : (mi == 1) ? Bk : (mi == 2) ? Bv : Bs;
    float*       O  = (mi == 0) ? outq : (mi == 1) ? outk : (mi == 2) ? outv : outs;
    int ldw = (mi == 3) ? OUT_CH : HO;      // weight/output leading dim (same)
    int lc0 = (g - mi * 5) * 64 + wv * 16;  // column base within this matrix
    int lr = lane & 15, lg = lane >> 4;

    f32x4 acc[4] = {};
    #pragma unroll
    for (int kc = 0; kc < K; kc += 32) {
        int kb = kc + lg * 8;
        // B fragment: lane holds B[kb+j][lc0+lr], j=0..7
        bf16x8 bfrag;
        const float* wp = W + (size_t)kb * ldw + lc0 + lr;
        #pragma unroll
        for (int j = 0; j < 8; j++) bfrag[j] = (bf16)wp[(size_t)j * ldw];
        #pragma unroll
        for (int mt = 0; mt < 4; mt++) {
            int row = row0 + mt * 16 + lr;
            int arow = (row < M) ? row : (M - 1);   // clamp: rows >= M discarded
            const float* ap = A + (size_t)arow * K + kb;
            bf16x8 afrag;
            #pragma unroll
            for (int j = 0; j < 8; j++) afrag[j] = (bf16)ap[j];
            acc[mt] = __builtin_amdgcn_mfma_f32_16x16x32_bf16(afrag, bfrag, acc[mt], 0, 0, 0);
        }
    }
    float bias = Bi[lc0 + lr];
    int col = lc0 + lr;
    #pragma unroll
    for (int mt = 0; mt < 4; mt++) {
        #pragma unroll
        for (int r = 0; r < 4; r++) {
            int row = row0 + mt * 16 + lg * 4 + r;   // C/D: col=lane&15, row=(lane>>4)*4+r
            if (row < M) O[(size_t)row * ldw + col] = acc[mt][r] + bias;
        }
    }
}

// ---------------- attention: one wave per destination node ----------------
__global__ __launch_bounds__(256) void attn_kernel(
    const float* __restrict__ q, const float* __restrict__ k, const float* __restrict__ v,
    const float* __restrict__ s, const int* __restrict__ row_ptr,
    const int* __restrict__ csr_src, float* __restrict__ out, int n)
{
    int wid  = blockIdx.x * 4 + (threadIdx.x >> 6);
    int lane = threadIdx.x & 63;
    if (wid >= n) return;

    float qr[HEADS];
    #pragma unroll
    for (int h = 0; h < HEADS; h++)
        qr[h] = q[(size_t)wid * HO + h * 64 + lane] * 0.125f;   // fold 1/sqrt(64)

    float m[HEADS], den[HEADS], acc[HEADS];
    #pragma unroll
    for (int h = 0; h < HEADS; h++) { m[h] = -1e30f; den[h] = 0.f; acc[h] = 0.f; }

    int e0 = row_ptr[wid], e1 = row_ptr[wid + 1];
    for (int e = e0; e < e1; e++) {
        int src = csr_src[e];
        size_t base = (size_t)src * HO + lane;
        float t[HEADS];
        #pragma unroll
        for (int h = 0; h < HEADS; h++) t[h] = qr[h] * k[base + h * 64];
        #pragma unroll
        for (int off = 32; off > 0; off >>= 1) {
            #pragma unroll
            for (int h = 0; h < HEADS; h++) t[h] += __shfl_xor(t[h], off, 64);
        }
        #pragma unroll
        for (int h = 0; h < HEADS; h++) {
            float a  = t[h];
            float mn = fmaxf(m[h], a);
            float sc = __expf(m[h] - mn);
            float p  = __expf(a - mn);
            den[h] = den[h] * sc + p;
            acc[h] = acc[h] * sc + p * v[base + h * 64];
            m[h] = mn;
        }
    }
    float r = 0.f;
    #pragma unroll
    for (int h = 0; h < HEADS; h++) r += (den[h] > 0.f) ? acc[h] / den[h] : 0.f;
    r = r * 0.2f + s[(size_t)wid * OUT_CH + lane];
    r = fmaxf(r, 0.f);
    out[(size_t)wid * OUT_CH + lane] = r;
}

// ---------------- launch ----------------

extern "C" void kernel_launch(void* const* d_in, const int* in_sizes, int n_in,
                              void* d_out, int out_size, void* d_ws, size_t ws_size,
                              hipStream_t stream)
{
    const float* x   = (const float*)d_in[0];
    const int*   ei  = (const int*)d_in[1];
    const int*   src = ei;
    const int*   dst = ei + N_EDGES;
    const float* q1w = (const float*)d_in[2];  const float* q1b = (const float*)d_in[3];
    const float* k1w = (const float*)d_in[4];  const float* k1b = (const float*)d_in[5];
    const float* v1w = (const float*)d_in[6];  const float* v1b = (const float*)d_in[7];
    const float* s1w = (const float*)d_in[8];  const float* s1b = (const float*)d_in[9];
    const float* q2w = (const float*)d_in[10]; const float* q2b = (const float*)d_in[11];
    const float* k2w = (const float*)d_in[12]; const float* k2b = (const float*)d_in[13];
    const float* v2w = (const float*)d_in[14]; const float* v2b = (const float*)d_in[15];
    const float* s2w = (const float*)d_in[16]; const float* s2b = (const float*)d_in[17];

    char* ws = (char*)d_ws;
    size_t off = 0;
    auto alloc = [&](size_t bytes) -> void* {
        void* p = ws + off;
        off += (bytes + 255) & ~(size_t)255;
        return p;
    };
    float* qbuf    = (float*)alloc((size_t)N_NODES * HO * 4);
    float* kbuf    = (float*)alloc((size_t)N_NODES * HO * 4);
    float* vbuf    = (float*)alloc((size_t)N_NODES * HO * 4);
    float* sbuf    = (float*)alloc((size_t)N_NODES * OUT_CH * 4);
    float* hbuf    = (float*)alloc((size_t)N_NODES * OUT_CH * 4);
    int*   row_ptr = (int*)  alloc((size_t)(N_NODES + 1) * 4);
    int*   cursor  = (int*)  alloc((size_t)N_NODES * 4);
    int*   counts  = (int*)  alloc((size_t)N_NODES * 4);
    int*   csr_src = (int*)  alloc((size_t)N_EDGES * 4);

    // CSR build (per call; must be stateless across replays)
    zero_kernel<<<(N_NODES + 255) / 256, 256, 0, stream>>>(counts, N_NODES);
    hist_kernel<<<(N_EDGES + 255) / 256, 256, 0, stream>>>(dst, counts, N_EDGES);
    scan_kernel<<<1, 1024, 0, stream>>>(counts, row_ptr, cursor, N_NODES);
    scatter_kernel<<<(N_EDGES + 255) / 256, 256, 0, stream>>>(src, dst, cursor, csr_src, N_EDGES);

    dim3 gg((N_NODES + 63) / 64, 16);

    // layer 1
    gemm_qkvs<IN_CH><<<gg, 256, 0, stream>>>(x, N_NODES,
        q1w, k1w, v1w, s1w, q1b, k1b, v1b, s1b, qbuf, kbuf, vbuf, sbuf);
    attn_kernel<<<(N_NODES + 3) / 4, 256, 0, stream>>>(
        qbuf, kbuf, vbuf, sbuf, row_ptr, csr_src, hbuf, N_NODES);

    // layer 2
    gemm_qkvs<OUT_CH><<<gg, 256, 0, stream>>>(hbuf, N_NODES,
        q2w, k2w, v2w, s2w, q2b, k2b, v2b, s2b, qbuf, kbuf, vbuf, sbuf);
    attn_kernel<<<(N_NODES + 3) / 4, 256, 0, stream>>>(
        qbuf, kbuf, vbuf, sbuf, row_ptr, csr_src, (float*)d_out, N_NODES);
}

// Round 3
// 272.451 us; speedup vs baseline: 1.0357x; 1.0357x over previous
//
#include <hip/hip_runtime.h>
#include <hip/hip_bf16.h>

#define N_NODES 10000
#define N_EDGES 160000
#define IN_CH   128
#define OUT_CH  64
#define HEADS   5
#define HO      320            // HEADS*OUT_CH
#define NN64    (N_NODES * 64)
#define PSTRIDE (2 * NN64)     // bf16 elems per head-pair plane

typedef __bf16 bf16;
typedef __bf16 bf16x8 __attribute__((ext_vector_type(8)));
typedef float  f32x4  __attribute__((ext_vector_type(4)));

__device__ inline float bflo(unsigned u) { return __builtin_bit_cast(float, u << 16); }
__device__ inline float bfhi(unsigned u) { return __builtin_bit_cast(float, u & 0xffff0000u); }

// ---------------- CSR build ----------------

__global__ void zero_kernel(int* __restrict__ p, int n) {
    int i = blockIdx.x * blockDim.x + threadIdx.x;
    if (i < n) p[i] = 0;
}

__global__ void hist_kernel(const int* __restrict__ dst, int* __restrict__ counts, int e) {
    int i = blockIdx.x * blockDim.x + threadIdx.x;
    if (i < e) atomicAdd(&counts[dst[i]], 1);
}

__global__ __launch_bounds__(1024) void scan_kernel(const int* __restrict__ counts,
                                                    int* __restrict__ row_ptr,
                                                    int* __restrict__ cursor, int n) {
    __shared__ int ls[1024];
    const int C = 10;                       // ceil(10000/1024)
    int t = threadIdx.x;
    int base = t * C;
    int local[C];
    int s = 0;
    #pragma unroll
    for (int i = 0; i < C; i++) {
        int idx = base + i;
        int c = (idx < n) ? counts[idx] : 0;
        local[i] = c; s += c;
    }
    ls[t] = s;
    __syncthreads();
    for (int off = 1; off < 1024; off <<= 1) {
        int v_ = (t >= off) ? ls[t - off] : 0;
        __syncthreads();
        ls[t] += v_;
        __syncthreads();
    }
    int ex = (t == 0) ? 0 : ls[t - 1];
    #pragma unroll
    for (int i = 0; i < C; i++) {
        int idx = base + i;
        if (idx < n) { row_ptr[idx] = ex; cursor[idx] = ex; ex += local[i]; }
    }
    if (t == 0) row_ptr[n] = ls[1023];
}

__global__ void scatter_kernel(const int* __restrict__ src, const int* __restrict__ dst,
                               int* __restrict__ cursor, int* __restrict__ csr_src, int e) {
    int i = blockIdx.x * blockDim.x + threadIdx.x;
    if (i < e) {
        int d = dst[i];
        int pos = atomicAdd(&cursor[d], 1);
        csr_src[pos] = src[i];
    }
}

// ---------------- fused QKV+skip GEMM (MFMA bf16, f32 in) ----------------
// A [M,K] f32 row-major; weights [K,width] f32 row-major.
// grid.y = 16 col-groups of 64: g 0-4 -> Q (f32), 5-9 -> K (bf16 packed),
// 10-14 -> V (bf16 packed), 15 -> skip (f32). Block = 4 waves, 64 rows x 64 cols.
// K/V packed layout: heads 0-3 -> [pair][node][chan][h&1] bf16 (dword = 2 heads),
// head 4 -> separate [node][chan] bf16 plane.
template<int K>
__global__ __launch_bounds__(256) void gemm_qkvs(
    const float* __restrict__ A, int M,
    const float* __restrict__ Wq, const float* __restrict__ Wk,
    const float* __restrict__ Wv, const float* __restrict__ Ws,
    const float* __restrict__ Bq, const float* __restrict__ Bk,
    const float* __restrict__ Bv, const float* __restrict__ Bs,
    float* __restrict__ outq, bf16* __restrict__ kp, bf16* __restrict__ k4,
    bf16* __restrict__ vp, bf16* __restrict__ v4, float* __restrict__ outs)
{
    int lane = threadIdx.x & 63;
    int wv   = threadIdx.x >> 6;
    int row0 = blockIdx.x * 64;
    int g    = blockIdx.y;
    int mi   = g / 5;                       // 0..3  (g=15 -> 3)
    const float* W  = (mi == 0) ? Wq : (mi == 1) ? Wk : (mi == 2) ? Wv : Ws;
    const float* Bi = (mi == 0) ? Bq : (mi == 1) ? Bk : (mi == 2) ? Bv : Bs;
    int ldw = (mi == 3) ? OUT_CH : HO;      // weight leading dim
    int lc0 = (g - mi * 5) * 64 + wv * 16;  // column base within this matrix
    int lr = lane & 15, lg = lane >> 4;

    f32x4 acc[4] = {};
    #pragma unroll
    for (int kc = 0; kc < K; kc += 32) {
        int kb = kc + lg * 8;
        // B fragment: lane holds B[kb+j][lc0+lr], j=0..7
        bf16x8 bfrag;
        const float* wp = W + (size_t)kb * ldw + lc0 + lr;
        #pragma unroll
        for (int j = 0; j < 8; j++) bfrag[j] = (bf16)wp[(size_t)j * ldw];
        #pragma unroll
        for (int mt = 0; mt < 4; mt++) {
            int row = row0 + mt * 16 + lr;
            int arow = (row < M) ? row : (M - 1);   // clamp: rows >= M discarded
            const f32x4* ap4 = reinterpret_cast<const f32x4*>(A + (size_t)arow * K + kb);
            f32x4 alo = ap4[0], ahi = ap4[1];
            bf16x8 afrag;
            #pragma unroll
            for (int j = 0; j < 4; j++) { afrag[j] = (bf16)alo[j]; afrag[j + 4] = (bf16)ahi[j]; }
            acc[mt] = __builtin_amdgcn_mfma_f32_16x16x32_bf16(afrag, bfrag, acc[mt], 0, 0, 0);
        }
    }
    float bias = Bi[lc0 + lr];
    int col  = lc0 + lr;                    // within-matrix column
    int head = col >> 6;                    // uniform per wave (lc0 mult of 16)
    int chan = col & 63;
    #pragma unroll
    for (int mt = 0; mt < 4; mt++) {
        #pragma unroll
        for (int r = 0; r < 4; r++) {
            int row = row0 + mt * 16 + lg * 4 + r;   // C/D: col=lane&15, row=(lane>>4)*4+r
            if (row >= M) continue;
            float val = acc[mt][r] + bias;
            if (mi == 0) {
                outq[(size_t)row * HO + col] = val;
            } else if (mi == 3) {
                outs[(size_t)row * OUT_CH + col] = val;
            } else {
                bf16* base4 = (mi == 1) ? k4 : v4;
                bf16* basep = (mi == 1) ? kp : vp;
                if (head == 4) base4[(size_t)row * 64 + chan] = (bf16)val;
                else basep[(size_t)(head >> 1) * PSTRIDE + ((size_t)row * 64 + chan) * 2 + (head & 1)] = (bf16)val;
            }
        }
    }
}

// ---------------- attention: one wave per destination node ----------------
// No max subtraction (logits bounded ~|10|; exp safe in f32; matches reference
// within fp rounding). Edge loop unrolled x2 for independent shuffle chains.
__global__ __launch_bounds__(256) void attn_kernel(
    const float* __restrict__ q, const bf16* __restrict__ kp, const bf16* __restrict__ k4,
    const bf16* __restrict__ vp, const bf16* __restrict__ v4,
    const float* __restrict__ s, const int* __restrict__ row_ptr,
    const int* __restrict__ csr_src, float* __restrict__ out, int n)
{
    int wid  = blockIdx.x * 4 + (threadIdx.x >> 6);
    int lane = threadIdx.x & 63;
    if (wid >= n) return;

    const unsigned* kp32 = (const unsigned*)kp;   // [2][N][64] dwords
    const unsigned* vp32 = (const unsigned*)vp;

    float qr[HEADS];
    #pragma unroll
    for (int h = 0; h < HEADS; h++)
        qr[h] = q[(size_t)wid * HO + h * 64 + lane] * 0.125f;   // fold 1/sqrt(64)

    float den[HEADS] = {}, acc[HEADS] = {};

    int e0 = row_ptr[wid], e1 = row_ptr[wid + 1];
    int e = e0;
    for (; e + 1 < e1; e += 2) {
        int sA = csr_src[e], sB = csr_src[e + 1];
        int oA = sA * 64 + lane, oB = sB * 64 + lane;
        // k loads (3 per edge)
        unsigned ka01 = kp32[oA], ka23 = kp32[NN64 + oA];
        unsigned kb01 = kp32[oB], kb23 = kp32[NN64 + oB];
        float ka4 = (float)k4[oA], kb4 = (float)k4[oB];
        // v loads (3 per edge)
        unsigned va01 = vp32[oA], va23 = vp32[NN64 + oA];
        unsigned vb01 = vp32[oB], vb23 = vp32[NN64 + oB];
        float va4 = (float)v4[oA], vb4 = (float)v4[oB];

        float tA[HEADS], tB[HEADS];
        tA[0] = qr[0] * bflo(ka01); tA[1] = qr[1] * bfhi(ka01);
        tA[2] = qr[2] * bflo(ka23); tA[3] = qr[3] * bfhi(ka23);
        tA[4] = qr[4] * ka4;
        tB[0] = qr[0] * bflo(kb01); tB[1] = qr[1] * bfhi(kb01);
        tB[2] = qr[2] * bflo(kb23); tB[3] = qr[3] * bfhi(kb23);
        tB[4] = qr[4] * kb4;
        #pragma unroll
        for (int off = 32; off > 0; off >>= 1) {
            #pragma unroll
            for (int h = 0; h < HEADS; h++) {
                tA[h] += __shfl_xor(tA[h], off, 64);
                tB[h] += __shfl_xor(tB[h], off, 64);
            }
        }
        float vA[HEADS] = { bflo(va01), bfhi(va01), bflo(va23), bfhi(va23), va4 };
        float vB[HEADS] = { bflo(vb01), bfhi(vb01), bflo(vb23), bfhi(vb23), vb4 };
        #pragma unroll
        for (int h = 0; h < HEADS; h++) {
            float pA = __expf(tA[h]), pB = __expf(tB[h]);
            den[h] += pA + pB;
            acc[h] += pA * vA[h] + pB * vB[h];
        }
    }
    if (e < e1) {                            // tail edge
        int sA = csr_src[e];
        int oA = sA * 64 + lane;
        unsigned ka01 = kp32[oA], ka23 = kp32[NN64 + oA];
        unsigned va01 = vp32[oA], va23 = vp32[NN64 + oA];
        float ka4 = (float)k4[oA], va4 = (float)v4[oA];
        float tA[HEADS];
        tA[0] = qr[0] * bflo(ka01); tA[1] = qr[1] * bfhi(ka01);
        tA[2] = qr[2] * bflo(ka23); tA[3] = qr[3] * bfhi(ka23);
        tA[4] = qr[4] * ka4;
        #pragma unroll
        for (int off = 32; off > 0; off >>= 1) {
            #pragma unroll
            for (int h = 0; h < HEADS; h++) tA[h] += __shfl_xor(tA[h], off, 64);
        }
        float vA[HEADS] = { bflo(va01), bfhi(va01), bflo(va23), bfhi(va23), va4 };
        #pragma unroll
        for (int h = 0; h < HEADS; h++) {
            float pA = __expf(tA[h]);
            den[h] += pA;
            acc[h] += pA * vA[h];
        }
    }
    float r = 0.f;
    #pragma unroll
    for (int h = 0; h < HEADS; h++) r += (den[h] > 0.f) ? acc[h] / den[h] : 0.f;
    r = r * 0.2f + s[(size_t)wid * OUT_CH + lane];
    r = fmaxf(r, 0.f);
    out[(size_t)wid * OUT_CH + lane] = r;
}

// ---------------- launch ----------------

extern "C" void kernel_launch(void* const* d_in, const int* in_sizes, int n_in,
                              void* d_out, int out_size, void* d_ws, size_t ws_size,
                              hipStream_t stream)
{
    const float* x   = (const float*)d_in[0];
    const int*   ei  = (const int*)d_in[1];
    const int*   src = ei;
    const int*   dst = ei + N_EDGES;
    const float* q1w = (const float*)d_in[2];  const float* q1b = (const float*)d_in[3];
    const float* k1w = (const float*)d_in[4];  const float* k1b = (const float*)d_in[5];
    const float* v1w = (const float*)d_in[6];  const float* v1b = (const float*)d_in[7];
    const float* s1w = (const float*)d_in[8];  const float* s1b = (const float*)d_in[9];
    const float* q2w = (const float*)d_in[10]; const float* q2b = (const float*)d_in[11];
    const float* k2w = (const float*)d_in[12]; const float* k2b = (const float*)d_in[13];
    const float* v2w = (const float*)d_in[14]; const float* v2b = (const float*)d_in[15];
    const float* s2w = (const float*)d_in[16]; const float* s2b = (const float*)d_in[17];

    char* ws = (char*)d_ws;
    size_t off = 0;
    auto alloc = [&](size_t bytes) -> void* {
        void* p = ws + off;
        off += (bytes + 255) & ~(size_t)255;
        return p;
    };
    float* qbuf    = (float*)alloc((size_t)N_NODES * HO * 4);
    bf16*  kpbuf   = (bf16*) alloc((size_t)2 * PSTRIDE * 2);   // 2 pairs x [N][64][2] bf16
    bf16*  k4buf   = (bf16*) alloc((size_t)NN64 * 2);
    bf16*  vpbuf   = (bf16*) alloc((size_t)2 * PSTRIDE * 2);
    bf16*  v4buf   = (bf16*) alloc((size_t)NN64 * 2);
    float* sbuf    = (float*)alloc((size_t)N_NODES * OUT_CH * 4);
    float* hbuf    = (float*)alloc((size_t)N_NODES * OUT_CH * 4);
    int*   row_ptr = (int*)  alloc((size_t)(N_NODES + 1) * 4);
    int*   cursor  = (int*)  alloc((size_t)N_NODES * 4);
    int*   counts  = (int*)  alloc((size_t)N_NODES * 4);
    int*   csr_src = (int*)  alloc((size_t)N_EDGES * 4);

    // CSR build (per call; stateless across replays)
    zero_kernel<<<(N_NODES + 255) / 256, 256, 0, stream>>>(counts, N_NODES);
    hist_kernel<<<(N_EDGES + 255) / 256, 256, 0, stream>>>(dst, counts, N_EDGES);
    scan_kernel<<<1, 1024, 0, stream>>>(counts, row_ptr, cursor, N_NODES);
    scatter_kernel<<<(N_EDGES + 255) / 256, 256, 0, stream>>>(src, dst, cursor, csr_src, N_EDGES);

    dim3 gg((N_NODES + 63) / 64, 16);

    // layer 1
    gemm_qkvs<IN_CH><<<gg, 256, 0, stream>>>(x, N_NODES,
        q1w, k1w, v1w, s1w, q1b, k1b, v1b, s1b,
        qbuf, kpbuf, k4buf, vpbuf, v4buf, sbuf);
    attn_kernel<<<(N_NODES + 3) / 4, 256, 0, stream>>>(
        qbuf, kpbuf, k4buf, vpbuf, v4buf, sbuf, row_ptr, csr_src, hbuf, N_NODES);

    // layer 2
    gemm_qkvs<OUT_CH><<<gg, 256, 0, stream>>>(hbuf, N_NODES,
        q2w, k2w, v2w, s2w, q2b, k2b, v2b, s2b,
        qbuf, kpbuf, k4buf, vpbuf, v4buf, sbuf);
    attn_kernel<<<(N_NODES + 3) / 4, 256, 0, stream>>>(
        qbuf, kpbuf, k4buf, vpbuf, v4buf, sbuf, row_ptr, csr_src, (float*)d_out, N_NODES);
}

// Round 4
// 204.643 us; speedup vs baseline: 1.3789x; 1.3314x over previous
//
#include <hip/hip_runtime.h>
#include <hip/hip_bf16.h>

#define N_NODES 10000
#define N_EDGES 160000
#define IN_CH   128
#define OUT_CH  64
#define HEADS   5
#define HO      320            // HEADS*OUT_CH
#define NN64    (N_NODES * 64)
#define PSTRIDE (2 * NN64)     // bf16 elems per head-pair plane

typedef __bf16 bf16;
typedef __bf16 bf16x8 __attribute__((ext_vector_type(8)));
typedef float  f32x4  __attribute__((ext_vector_type(4)));
typedef unsigned u32;

__device__ inline float bflo(u32 u) { return __builtin_bit_cast(float, u << 16); }
__device__ inline float bfhi(u32 u) { return __builtin_bit_cast(float, u & 0xffff0000u); }

// ---------------- CSR build ----------------

__global__ void hist_kernel(const int* __restrict__ dst, int* __restrict__ counts, int e) {
    int i = blockIdx.x * blockDim.x + threadIdx.x;
    if (i < e) atomicAdd(&counts[dst[i]], 1);
}

__global__ __launch_bounds__(1024) void scan_kernel(const int* __restrict__ counts,
                                                    int* __restrict__ row_ptr,
                                                    int* __restrict__ cursor, int n) {
    __shared__ int ls[1024];
    const int C = 10;                       // ceil(10000/1024)
    int t = threadIdx.x;
    int base = t * C;
    int local[C];
    int s = 0;
    #pragma unroll
    for (int i = 0; i < C; i++) {
        int idx = base + i;
        int c = (idx < n) ? counts[idx] : 0;
        local[i] = c; s += c;
    }
    ls[t] = s;
    __syncthreads();
    for (int off = 1; off < 1024; off <<= 1) {
        int v_ = (t >= off) ? ls[t - off] : 0;
        __syncthreads();
        ls[t] += v_;
        __syncthreads();
    }
    int ex = (t == 0) ? 0 : ls[t - 1];
    #pragma unroll
    for (int i = 0; i < C; i++) {
        int idx = base + i;
        if (idx < n) { row_ptr[idx] = ex; cursor[idx] = ex; ex += local[i]; }
    }
    if (t == 0) row_ptr[n] = ls[1023];
}

__global__ void scatter_kernel(const int* __restrict__ src, const int* __restrict__ dst,
                               int* __restrict__ cursor, int* __restrict__ csr_src, int e) {
    int i = blockIdx.x * blockDim.x + threadIdx.x;
    if (i < e) {
        int d = dst[i];
        int pos = atomicAdd(&cursor[d], 1);
        csr_src[pos] = src[i];
    }
}

// ---------------- fused QKV+skip GEMM (MFMA bf16, f32 in) ----------------
// (unchanged from Round 3 — passed, not the bottleneck)
template<int K>
__global__ __launch_bounds__(256) void gemm_qkvs(
    const float* __restrict__ A, int M,
    const float* __restrict__ Wq, const float* __restrict__ Wk,
    const float* __restrict__ Wv, const float* __restrict__ Ws,
    const float* __restrict__ Bq, const float* __restrict__ Bk,
    const float* __restrict__ Bv, const float* __restrict__ Bs,
    float* __restrict__ outq, bf16* __restrict__ kp, bf16* __restrict__ k4,
    bf16* __restrict__ vp, bf16* __restrict__ v4, float* __restrict__ outs)
{
    int lane = threadIdx.x & 63;
    int wv   = threadIdx.x >> 6;
    int row0 = blockIdx.x * 64;
    int g    = blockIdx.y;
    int mi   = g / 5;                       // 0..3  (g=15 -> 3)
    const float* W  = (mi == 0) ? Wq : (mi == 1) ? Wk : (mi == 2) ? Wv : Ws;
    const float* Bi = (mi == 0) ? Bq : (mi == 1) ? Bk : (mi == 2) ? Bv : Bs;
    int ldw = (mi == 3) ? OUT_CH : HO;      // weight leading dim
    int lc0 = (g - mi * 5) * 64 + wv * 16;  // column base within this matrix
    int lr = lane & 15, lg = lane >> 4;

    f32x4 acc[4] = {};
    #pragma unroll
    for (int kc = 0; kc < K; kc += 32) {
        int kb = kc + lg * 8;
        bf16x8 bfrag;
        const float* wp = W + (size_t)kb * ldw + lc0 + lr;
        #pragma unroll
        for (int j = 0; j < 8; j++) bfrag[j] = (bf16)wp[(size_t)j * ldw];
        #pragma unroll
        for (int mt = 0; mt < 4; mt++) {
            int row = row0 + mt * 16 + lr;
            int arow = (row < M) ? row : (M - 1);   // clamp: rows >= M discarded
            const f32x4* ap4 = reinterpret_cast<const f32x4*>(A + (size_t)arow * K + kb);
            f32x4 alo = ap4[0], ahi = ap4[1];
            bf16x8 afrag;
            #pragma unroll
            for (int j = 0; j < 4; j++) { afrag[j] = (bf16)alo[j]; afrag[j + 4] = (bf16)ahi[j]; }
            acc[mt] = __builtin_amdgcn_mfma_f32_16x16x32_bf16(afrag, bfrag, acc[mt], 0, 0, 0);
        }
    }
    float bias = Bi[lc0 + lr];
    int col  = lc0 + lr;
    int head = col >> 6;                    // uniform per wave
    int chan = col & 63;
    #pragma unroll
    for (int mt = 0; mt < 4; mt++) {
        #pragma unroll
        for (int r = 0; r < 4; r++) {
            int row = row0 + mt * 16 + lg * 4 + r;
            if (row >= M) continue;
            float val = acc[mt][r] + bias;
            if (mi == 0) {
                outq[(size_t)row * HO + col] = val;
            } else if (mi == 3) {
                outs[(size_t)row * OUT_CH + col] = val;
            } else {
                bf16* base4 = (mi == 1) ? k4 : v4;
                bf16* basep = (mi == 1) ? kp : vp;
                if (head == 4) base4[(size_t)row * 64 + chan] = (bf16)val;
                else basep[(size_t)(head >> 1) * PSTRIDE + ((size_t)row * 64 + chan) * 2 + (head & 1)] = (bf16)val;
            }
        }
    }
}

// ---------------- attention: one wave per node, 4 edges x 16 lanes ----------------
// Lane = 4 consecutive channels (all 5 heads); quarter (lane>>4) = edge slot.
// Reduce depth 4 (within 16-lane group) instead of 6 (64 lanes); one final
// 2-level cross-quarter combine. No max subtraction (logits bounded; f32 safe).
__global__ __launch_bounds__(256) void attn_kernel(
    const float* __restrict__ q, const bf16* __restrict__ kp, const bf16* __restrict__ k4,
    const bf16* __restrict__ vp, const bf16* __restrict__ v4,
    const float* __restrict__ s, const int* __restrict__ row_ptr,
    const int* __restrict__ csr_src, float* __restrict__ out, int n)
{
    int wid  = blockIdx.x * 4 + (threadIdx.x >> 6);
    int lane = threadIdx.x & 63;
    if (wid >= n) return;
    int lr  = lane & 15;        // channel group: channels 4lr..4lr+3
    int qtr = lane >> 4;        // edge slot within iteration

    const u32* kp32 = (const u32*)kp;   // [2][N][64] dwords (head pairs)
    const u32* vp32 = (const u32*)vp;
    const u32* k432 = (const u32*)k4;   // [N][32] dwords (head 4, 2 ch/dword)
    const u32* v432 = (const u32*)v4;

    f32x4 qr[HEADS];
    #pragma unroll
    for (int h = 0; h < HEADS; h++) {
        f32x4 t = *reinterpret_cast<const f32x4*>(q + (size_t)wid * HO + h * 64 + 4 * lr);
        qr[h] = t * 0.125f;             // fold 1/sqrt(64)
    }

    float den0 = 0, den1 = 0, den2 = 0, den3 = 0, den4 = 0;
    f32x4 ac0 = {}, ac1 = {}, ac2 = {}, ac3 = {}, ac4 = {};

    int e0 = row_ptr[wid], e1 = row_ptr[wid + 1];
    for (int eb = e0; eb < e1; eb += 4) {
        int  eidx  = eb + qtr;
        bool valid = eidx < e1;
        int  src   = csr_src[valid ? eidx : e0];

        const u32* kpb = kp32 + (size_t)src * 64 + 4 * lr;
        uint4 kA = *reinterpret_cast<const uint4*>(kpb);
        uint4 kB = *reinterpret_cast<const uint4*>(kpb + NN64);
        uint2 kC = *reinterpret_cast<const uint2*>(k432 + (size_t)src * 32 + 2 * lr);
        const u32* vpb = vp32 + (size_t)src * 64 + 4 * lr;
        uint4 vA = *reinterpret_cast<const uint4*>(vpb);
        uint4 vB = *reinterpret_cast<const uint4*>(vpb + NN64);
        uint2 vC = *reinterpret_cast<const uint2*>(v432 + (size_t)src * 32 + 2 * lr);

        float t0 = qr[0][0]*bflo(kA.x) + qr[0][1]*bflo(kA.y) + qr[0][2]*bflo(kA.z) + qr[0][3]*bflo(kA.w);
        float t1 = qr[1][0]*bfhi(kA.x) + qr[1][1]*bfhi(kA.y) + qr[1][2]*bfhi(kA.z) + qr[1][3]*bfhi(kA.w);
        float t2 = qr[2][0]*bflo(kB.x) + qr[2][1]*bflo(kB.y) + qr[2][2]*bflo(kB.z) + qr[2][3]*bflo(kB.w);
        float t3 = qr[3][0]*bfhi(kB.x) + qr[3][1]*bfhi(kB.y) + qr[3][2]*bfhi(kB.z) + qr[3][3]*bfhi(kB.w);
        float t4 = qr[4][0]*bflo(kC.x) + qr[4][1]*bfhi(kC.x) + qr[4][2]*bflo(kC.y) + qr[4][3]*bfhi(kC.y);

        #pragma unroll
        for (int m = 1; m <= 8; m <<= 1) {
            t0 += __shfl_xor(t0, m, 64);
            t1 += __shfl_xor(t1, m, 64);
            t2 += __shfl_xor(t2, m, 64);
            t3 += __shfl_xor(t3, m, 64);
            t4 += __shfl_xor(t4, m, 64);
        }
        float p0 = valid ? __expf(t0) : 0.f;
        float p1 = valid ? __expf(t1) : 0.f;
        float p2 = valid ? __expf(t2) : 0.f;
        float p3 = valid ? __expf(t3) : 0.f;
        float p4 = valid ? __expf(t4) : 0.f;
        den0 += p0; den1 += p1; den2 += p2; den3 += p3; den4 += p4;

        ac0[0] += p0*bflo(vA.x); ac0[1] += p0*bflo(vA.y); ac0[2] += p0*bflo(vA.z); ac0[3] += p0*bflo(vA.w);
        ac1[0] += p1*bfhi(vA.x); ac1[1] += p1*bfhi(vA.y); ac1[2] += p1*bfhi(vA.z); ac1[3] += p1*bfhi(vA.w);
        ac2[0] += p2*bflo(vB.x); ac2[1] += p2*bflo(vB.y); ac2[2] += p2*bflo(vB.z); ac2[3] += p2*bflo(vB.w);
        ac3[0] += p3*bfhi(vB.x); ac3[1] += p3*bfhi(vB.y); ac3[2] += p3*bfhi(vB.z); ac3[3] += p3*bfhi(vB.w);
        ac4[0] += p4*bflo(vC.x); ac4[1] += p4*bfhi(vC.x); ac4[2] += p4*bflo(vC.y); ac4[3] += p4*bfhi(vC.y);
    }

    // combine the 4 edge-slot partials (lanes l, l+16, l+32, l+48)
    #pragma unroll
    for (int m = 16; m <= 32; m <<= 1) {
        den0 += __shfl_xor(den0, m, 64);
        den1 += __shfl_xor(den1, m, 64);
        den2 += __shfl_xor(den2, m, 64);
        den3 += __shfl_xor(den3, m, 64);
        den4 += __shfl_xor(den4, m, 64);
        #pragma unroll
        for (int j = 0; j < 4; j++) {
            ac0[j] += __shfl_xor(ac0[j], m, 64);
            ac1[j] += __shfl_xor(ac1[j], m, 64);
            ac2[j] += __shfl_xor(ac2[j], m, 64);
            ac3[j] += __shfl_xor(ac3[j], m, 64);
            ac4[j] += __shfl_xor(ac4[j], m, 64);
        }
    }

    if (qtr == 0) {
        float i0 = (den0 > 0.f) ? 1.f / den0 : 0.f;
        float i1 = (den1 > 0.f) ? 1.f / den1 : 0.f;
        float i2 = (den2 > 0.f) ? 1.f / den2 : 0.f;
        float i3 = (den3 > 0.f) ? 1.f / den3 : 0.f;
        float i4 = (den4 > 0.f) ? 1.f / den4 : 0.f;
        f32x4 sv = *reinterpret_cast<const f32x4*>(s + (size_t)wid * OUT_CH + 4 * lr);
        f32x4 r;
        #pragma unroll
        for (int j = 0; j < 4; j++) {
            float sum = ac0[j]*i0 + ac1[j]*i1 + ac2[j]*i2 + ac3[j]*i3 + ac4[j]*i4;
            r[j] = fmaxf(sum * 0.2f + sv[j], 0.f);
        }
        *reinterpret_cast<f32x4*>(out + (size_t)wid * OUT_CH + 4 * lr) = r;
    }
}

// ---------------- launch ----------------

extern "C" void kernel_launch(void* const* d_in, const int* in_sizes, int n_in,
                              void* d_out, int out_size, void* d_ws, size_t ws_size,
                              hipStream_t stream)
{
    const float* x   = (const float*)d_in[0];
    const int*   ei  = (const int*)d_in[1];
    const int*   src = ei;
    const int*   dst = ei + N_EDGES;
    const float* q1w = (const float*)d_in[2];  const float* q1b = (const float*)d_in[3];
    const float* k1w = (const float*)d_in[4];  const float* k1b = (const float*)d_in[5];
    const float* v1w = (const float*)d_in[6];  const float* v1b = (const float*)d_in[7];
    const float* s1w = (const float*)d_in[8];  const float* s1b = (const float*)d_in[9];
    const float* q2w = (const float*)d_in[10]; const float* q2b = (const float*)d_in[11];
    const float* k2w = (const float*)d_in[12]; const float* k2b = (const float*)d_in[13];
    const float* v2w = (const float*)d_in[14]; const float* v2b = (const float*)d_in[15];
    const float* s2w = (const float*)d_in[16]; const float* s2b = (const float*)d_in[17];

    char* ws = (char*)d_ws;
    size_t off = 0;
    auto alloc = [&](size_t bytes) -> void* {
        void* p = ws + off;
        off += (bytes + 255) & ~(size_t)255;
        return p;
    };
    float* qbuf    = (float*)alloc((size_t)N_NODES * HO * 4);
    bf16*  kpbuf   = (bf16*) alloc((size_t)2 * PSTRIDE * 2);   // 2 pairs x [N][64][2] bf16
    bf16*  k4buf   = (bf16*) alloc((size_t)NN64 * 2);
    bf16*  vpbuf   = (bf16*) alloc((size_t)2 * PSTRIDE * 2);
    bf16*  v4buf   = (bf16*) alloc((size_t)NN64 * 2);
    float* sbuf    = (float*)alloc((size_t)N_NODES * OUT_CH * 4);
    float* hbuf    = (float*)alloc((size_t)N_NODES * OUT_CH * 4);
    int*   row_ptr = (int*)  alloc((size_t)(N_NODES + 1) * 4);
    int*   cursor  = (int*)  alloc((size_t)N_NODES * 4);
    int*   counts  = (int*)  alloc((size_t)N_NODES * 4);
    int*   csr_src = (int*)  alloc((size_t)N_EDGES * 4);

    // CSR build (per call; stateless across replays)
    hipMemsetAsync(counts, 0, (size_t)N_NODES * 4, stream);
    hist_kernel<<<(N_EDGES + 255) / 256, 256, 0, stream>>>(dst, counts, N_EDGES);
    scan_kernel<<<1, 1024, 0, stream>>>(counts, row_ptr, cursor, N_NODES);
    scatter_kernel<<<(N_EDGES + 255) / 256, 256, 0, stream>>>(src, dst, cursor, csr_src, N_EDGES);

    dim3 gg((N_NODES + 63) / 64, 16);

    // layer 1
    gemm_qkvs<IN_CH><<<gg, 256, 0, stream>>>(x, N_NODES,
        q1w, k1w, v1w, s1w, q1b, k1b, v1b, s1b,
        qbuf, kpbuf, k4buf, vpbuf, v4buf, sbuf);
    attn_kernel<<<(N_NODES + 3) / 4, 256, 0, stream>>>(
        qbuf, kpbuf, k4buf, vpbuf, v4buf, sbuf, row_ptr, csr_src, hbuf, N_NODES);

    // layer 2
    gemm_qkvs<OUT_CH><<<gg, 256, 0, stream>>>(hbuf, N_NODES,
        q2w, k2w, v2w, s2w, q2b, k2b, v2b, s2b,
        qbuf, kpbuf, k4buf, vpbuf, v4buf, sbuf);
    attn_kernel<<<(N_NODES + 3) / 4, 256, 0, stream>>>(
        qbuf, kpbuf, k4buf, vpbuf, v4buf, sbuf, row_ptr, csr_src, (float*)d_out, N_NODES);
}

// Round 5
// 150.144 us; speedup vs baseline: 1.8794x; 1.3630x over previous
//
#include <hip/hip_runtime.h>
#include <hip/hip_bf16.h>

#define N_NODES 10000
#define N_EDGES 160000
#define IN_CH   128
#define OUT_CH  64
#define HEADS   5
#define HO      320            // HEADS*OUT_CH
#define NN64    (N_NODES * 64)

typedef __bf16 bf16;
typedef __bf16 bf16x8 __attribute__((ext_vector_type(8)));
typedef float  f32x4  __attribute__((ext_vector_type(4)));
typedef unsigned u32;

__device__ inline float bflo(u32 u) { return __builtin_bit_cast(float, u << 16); }
__device__ inline float bfhi(u32 u) { return __builtin_bit_cast(float, u & 0xffff0000u); }

// ---------------- CSR build ----------------

__global__ void hist_kernel(const int* __restrict__ dst, int* __restrict__ counts, int e) {
    int i = blockIdx.x * blockDim.x + threadIdx.x;
    if (i < e) atomicAdd(&counts[dst[i]], 1);
}

__global__ __launch_bounds__(1024) void scan_kernel(const int* __restrict__ counts,
                                                    int* __restrict__ row_ptr,
                                                    int* __restrict__ cursor, int n) {
    __shared__ int ls[1024];
    const int C = 10;
    int t = threadIdx.x;
    int base = t * C;
    int local[C];
    int s = 0;
    #pragma unroll
    for (int i = 0; i < C; i++) {
        int idx = base + i;
        int c = (idx < n) ? counts[idx] : 0;
        local[i] = c; s += c;
    }
    ls[t] = s;
    __syncthreads();
    for (int off = 1; off < 1024; off <<= 1) {
        int v_ = (t >= off) ? ls[t - off] : 0;
        __syncthreads();
        ls[t] += v_;
        __syncthreads();
    }
    int ex = (t == 0) ? 0 : ls[t - 1];
    #pragma unroll
    for (int i = 0; i < C; i++) {
        int idx = base + i;
        if (idx < n) { row_ptr[idx] = ex; cursor[idx] = ex; ex += local[i]; }
    }
    if (t == 0) row_ptr[n] = ls[1023];
}

__global__ void scatter_kernel(const int* __restrict__ src, const int* __restrict__ dst,
                               int* __restrict__ cursor, int* __restrict__ csr_src, int e) {
    int i = blockIdx.x * blockDim.x + threadIdx.x;
    if (i < e) {
        int d = dst[i];
        int pos = atomicAdd(&cursor[d], 1);
        csr_src[pos] = src[i];
    }
}

// ---------------- weight repack: f32 [K][NC] -> bf16 MFMA-B-fragment order ----------
// pk[((ct_g*(K/32) + kc)*64 + lane)*8 + j] = W[kc*32 + (lane>>4)*8 + j][ct_g*16 + (lane&15)]
__device__ inline void repack_one(const float* __restrict__ w, bf16* __restrict__ p,
                                  int i, int K, int NC) {
    int j    = i & 7;
    int lane = (i >> 3) & 63;
    int unit = i >> 9;
    int nkc  = K >> 5;
    int kc   = unit % nkc;
    int ctg  = unit / nkc;
    int col  = ctg * 16 + (lane & 15);
    int k    = kc * 32 + (lane >> 4) * 8 + j;
    p[i] = (bf16)w[(size_t)k * NC + col];
}

__global__ __launch_bounds__(256) void repack_weights(
    const float* q1, const float* k1, const float* v1, const float* s1,
    const float* q2, const float* k2, const float* v2, const float* s2,
    bf16* pq1, bf16* pk1, bf16* pv1, bf16* ps1,
    bf16* pq2, bf16* pk2, bf16* pv2, bf16* ps2)
{
    int t = blockIdx.x * 256 + threadIdx.x;           // 196608 total
    if      (t <  40960) repack_one(q1, pq1, t,           128, 320);
    else if (t <  81920) repack_one(k1, pk1, t -  40960,  128, 320);
    else if (t < 122880) repack_one(v1, pv1, t -  81920,  128, 320);
    else if (t < 131072) repack_one(s1, ps1, t - 122880,  128,  64);
    else if (t < 151552) repack_one(q2, pq2, t - 131072,   64, 320);
    else if (t < 172032) repack_one(k2, pk2, t - 151552,   64, 320);
    else if (t < 192512) repack_one(v2, pv2, t - 172032,   64, 320);
    else                 repack_one(s2, ps2, t - 192512,   64,  64);
}

// ---------------- fused QKV+skip GEMM (register-A, packed-B) ----------------
// grid (157, 4): blockIdx.x = 64-row stripe, blockIdx.y = gb:
//   gb 0/1/2 -> Q/K/V head-pairs (0,1),(2,3) -> u32 pair planes
//   gb 3     -> singles: Q h4, K h4, V h4 (bf16 planes) + skip (f32)
// Wave = 16 rows; A-frags loaded once, reused for all col-groups.
template<int K>
__global__ __launch_bounds__(256) void gemm_fused(
    const float* __restrict__ A, int M,
    const bf16* __restrict__ pq, const bf16* __restrict__ pk,
    const bf16* __restrict__ pv, const bf16* __restrict__ ps,
    const float* __restrict__ Bq, const float* __restrict__ Bk,
    const float* __restrict__ Bv, const float* __restrict__ Bs,
    u32* __restrict__ qp, bf16* __restrict__ q4,
    u32* __restrict__ kp, bf16* __restrict__ k4,
    u32* __restrict__ vp, bf16* __restrict__ v4,
    float* __restrict__ sout)
{
    constexpr int NKC = K / 32;
    int lane = threadIdx.x & 63;
    int wv   = threadIdx.x >> 6;
    int lr = lane & 15, lg = lane >> 4;
    int rw0 = blockIdx.x * 64 + wv * 16;   // wave's 16-row base
    int gb  = blockIdx.y;

    bf16x8 afrag[NKC];
    {
        int arow = rw0 + lr; if (arow > M - 1) arow = M - 1;
        const float* ap = A + (size_t)arow * K + lg * 8;
        #pragma unroll
        for (int kc = 0; kc < NKC; kc++) {
            f32x4 lo = *reinterpret_cast<const f32x4*>(ap + kc * 32);
            f32x4 hi = *reinterpret_cast<const f32x4*>(ap + kc * 32 + 4);
            #pragma unroll
            for (int j = 0; j < 4; j++) { afrag[kc][j] = (bf16)lo[j]; afrag[kc][j + 4] = (bf16)hi[j]; }
        }
    }

    if (gb < 3) {
        const bf16*  P  = (gb == 0) ? pq : (gb == 1) ? pk : pv;
        const float* Bb = (gb == 0) ? Bq : (gb == 1) ? Bk : Bv;
        u32*         PP = (gb == 0) ? qp : (gb == 1) ? kp : vp;
        #pragma unroll
        for (int ph = 0; ph < 2; ph++) {
            f32x4 acc0[4] = {}; f32x4 acc1[4] = {};
            #pragma unroll
            for (int ct = 0; ct < 4; ct++) {
                #pragma unroll
                for (int kc = 0; kc < NKC; kc++) {
                    bf16x8 b0 = *reinterpret_cast<const bf16x8*>(
                        P + ((size_t)((2 * ph + 0) * 4 + ct) * NKC + kc) * 512 + lane * 8);
                    bf16x8 b1 = *reinterpret_cast<const bf16x8*>(
                        P + ((size_t)((2 * ph + 1) * 4 + ct) * NKC + kc) * 512 + lane * 8);
                    acc0[ct] = __builtin_amdgcn_mfma_f32_16x16x32_bf16(afrag[kc], b0, acc0[ct], 0, 0, 0);
                    acc1[ct] = __builtin_amdgcn_mfma_f32_16x16x32_bf16(afrag[kc], b1, acc1[ct], 0, 0, 0);
                }
            }
            u32* plane = PP + (size_t)ph * NN64;
            #pragma unroll
            for (int ct = 0; ct < 4; ct++) {
                int chan = ct * 16 + lr;
                float b0 = Bb[(2 * ph + 0) * 64 + chan];
                float b1 = Bb[(2 * ph + 1) * 64 + chan];
                #pragma unroll
                for (int r = 0; r < 4; r++) {
                    int row = rw0 + lg * 4 + r;
                    if (row >= M) continue;
                    u32 lo = __builtin_bit_cast(unsigned short, (bf16)(acc0[ct][r] + b0));
                    u32 hi = __builtin_bit_cast(unsigned short, (bf16)(acc1[ct][r] + b1));
                    plane[(size_t)row * 64 + chan] = lo | (hi << 16);
                }
            }
        }
    } else {
        #pragma unroll
        for (int su = 0; su < 4; su++) {
            const bf16*  P  = (su == 0) ? pq : (su == 1) ? pk : (su == 2) ? pv : ps;
            const float* Bb = (su == 0) ? Bq : (su == 1) ? Bk : (su == 2) ? Bv : Bs;
            int ctg0 = (su < 3) ? 16 : 0;     // head-4 cols live at ct_g 16..19
            f32x4 acc[4] = {};
            #pragma unroll
            for (int ct = 0; ct < 4; ct++) {
                #pragma unroll
                for (int kc = 0; kc < NKC; kc++) {
                    bf16x8 b = *reinterpret_cast<const bf16x8*>(
                        P + ((size_t)(ctg0 + ct) * NKC + kc) * 512 + lane * 8);
                    acc[ct] = __builtin_amdgcn_mfma_f32_16x16x32_bf16(afrag[kc], b, acc[ct], 0, 0, 0);
                }
            }
            #pragma unroll
            for (int ct = 0; ct < 4; ct++) {
                int chan = ct * 16 + lr;
                float bb = (su < 3) ? Bb[256 + chan] : Bb[chan];
                #pragma unroll
                for (int r = 0; r < 4; r++) {
                    int row = rw0 + lg * 4 + r;
                    if (row >= M) continue;
                    float val = acc[ct][r] + bb;
                    if      (su == 0) q4[(size_t)row * 64 + chan] = (bf16)val;
                    else if (su == 1) k4[(size_t)row * 64 + chan] = (bf16)val;
                    else if (su == 2) v4[(size_t)row * 64 + chan] = (bf16)val;
                    else              sout[(size_t)row * 64 + chan] = val;
                }
            }
        }
    }
}

// ---------------- attention: one wave per node, 4 edges x 16 lanes ----------------
__global__ __launch_bounds__(256) void attn_kernel(
    const u32* __restrict__ qp, const bf16* __restrict__ q4,
    const u32* __restrict__ kp, const bf16* __restrict__ k4,
    const u32* __restrict__ vp, const bf16* __restrict__ v4,
    const float* __restrict__ s, const int* __restrict__ row_ptr,
    const int* __restrict__ csr_src, float* __restrict__ out, int n)
{
    int wid  = blockIdx.x * 4 + (threadIdx.x >> 6);
    int lane = threadIdx.x & 63;
    if (wid >= n) return;
    int lr  = lane & 15;        // channel group: channels 4lr..4lr+3
    int qtr = lane >> 4;        // edge slot within iteration

    const u32* k432 = (const u32*)k4;   // [N][32] dwords (head 4, 2 ch/dword)
    const u32* v432 = (const u32*)v4;
    const u32* q432 = (const u32*)q4;

    f32x4 qr[HEADS];
    {
        uint4 qA = *reinterpret_cast<const uint4*>(qp + (size_t)wid * 64 + 4 * lr);
        uint4 qB = *reinterpret_cast<const uint4*>(qp + NN64 + (size_t)wid * 64 + 4 * lr);
        uint2 qC = *reinterpret_cast<const uint2*>(q432 + (size_t)wid * 32 + 2 * lr);
        qr[0] = f32x4{bflo(qA.x), bflo(qA.y), bflo(qA.z), bflo(qA.w)} * 0.125f;
        qr[1] = f32x4{bfhi(qA.x), bfhi(qA.y), bfhi(qA.z), bfhi(qA.w)} * 0.125f;
        qr[2] = f32x4{bflo(qB.x), bflo(qB.y), bflo(qB.z), bflo(qB.w)} * 0.125f;
        qr[3] = f32x4{bfhi(qB.x), bfhi(qB.y), bfhi(qB.z), bfhi(qB.w)} * 0.125f;
        qr[4] = f32x4{bflo(qC.x), bfhi(qC.x), bflo(qC.y), bfhi(qC.y)} * 0.125f;
    }

    float den0 = 0, den1 = 0, den2 = 0, den3 = 0, den4 = 0;
    f32x4 ac0 = {}, ac1 = {}, ac2 = {}, ac3 = {}, ac4 = {};

    int e0 = row_ptr[wid], e1 = row_ptr[wid + 1];
    for (int eb = e0; eb < e1; eb += 4) {
        int  eidx  = eb + qtr;
        bool valid = eidx < e1;
        int  src   = csr_src[valid ? eidx : e0];

        const u32* kpb = kp + (size_t)src * 64 + 4 * lr;
        uint4 kA = *reinterpret_cast<const uint4*>(kpb);
        uint4 kB = *reinterpret_cast<const uint4*>(kpb + NN64);
        uint2 kC = *reinterpret_cast<const uint2*>(k432 + (size_t)src * 32 + 2 * lr);
        const u32* vpb = vp + (size_t)src * 64 + 4 * lr;
        uint4 vA = *reinterpret_cast<const uint4*>(vpb);
        uint4 vB = *reinterpret_cast<const uint4*>(vpb + NN64);
        uint2 vC = *reinterpret_cast<const uint2*>(v432 + (size_t)src * 32 + 2 * lr);

        float t0 = qr[0][0]*bflo(kA.x) + qr[0][1]*bflo(kA.y) + qr[0][2]*bflo(kA.z) + qr[0][3]*bflo(kA.w);
        float t1 = qr[1][0]*bfhi(kA.x) + qr[1][1]*bfhi(kA.y) + qr[1][2]*bfhi(kA.z) + qr[1][3]*bfhi(kA.w);
        float t2 = qr[2][0]*bflo(kB.x) + qr[2][1]*bflo(kB.y) + qr[2][2]*bflo(kB.z) + qr[2][3]*bflo(kB.w);
        float t3 = qr[3][0]*bfhi(kB.x) + qr[3][1]*bfhi(kB.y) + qr[3][2]*bfhi(kB.z) + qr[3][3]*bfhi(kB.w);
        float t4 = qr[4][0]*bflo(kC.x) + qr[4][1]*bfhi(kC.x) + qr[4][2]*bflo(kC.y) + qr[4][3]*bfhi(kC.y);

        #pragma unroll
        for (int m = 1; m <= 8; m <<= 1) {
            t0 += __shfl_xor(t0, m, 64);
            t1 += __shfl_xor(t1, m, 64);
            t2 += __shfl_xor(t2, m, 64);
            t3 += __shfl_xor(t3, m, 64);
            t4 += __shfl_xor(t4, m, 64);
        }
        float p0 = valid ? __expf(t0) : 0.f;
        float p1 = valid ? __expf(t1) : 0.f;
        float p2 = valid ? __expf(t2) : 0.f;
        float p3 = valid ? __expf(t3) : 0.f;
        float p4 = valid ? __expf(t4) : 0.f;
        den0 += p0; den1 += p1; den2 += p2; den3 += p3; den4 += p4;

        ac0[0] += p0*bflo(vA.x); ac0[1] += p0*bflo(vA.y); ac0[2] += p0*bflo(vA.z); ac0[3] += p0*bflo(vA.w);
        ac1[0] += p1*bfhi(vA.x); ac1[1] += p1*bfhi(vA.y); ac1[2] += p1*bfhi(vA.z); ac1[3] += p1*bfhi(vA.w);
        ac2[0] += p2*bflo(vB.x); ac2[1] += p2*bflo(vB.y); ac2[2] += p2*bflo(vB.z); ac2[3] += p2*bflo(vB.w);
        ac3[0] += p3*bfhi(vB.x); ac3[1] += p3*bfhi(vB.y); ac3[2] += p3*bfhi(vB.z); ac3[3] += p3*bfhi(vB.w);
        ac4[0] += p4*bflo(vC.x); ac4[1] += p4*bfhi(vC.x); ac4[2] += p4*bflo(vC.y); ac4[3] += p4*bfhi(vC.y);
    }

    #pragma unroll
    for (int m = 16; m <= 32; m <<= 1) {
        den0 += __shfl_xor(den0, m, 64);
        den1 += __shfl_xor(den1, m, 64);
        den2 += __shfl_xor(den2, m, 64);
        den3 += __shfl_xor(den3, m, 64);
        den4 += __shfl_xor(den4, m, 64);
        #pragma unroll
        for (int j = 0; j < 4; j++) {
            ac0[j] += __shfl_xor(ac0[j], m, 64);
            ac1[j] += __shfl_xor(ac1[j], m, 64);
            ac2[j] += __shfl_xor(ac2[j], m, 64);
            ac3[j] += __shfl_xor(ac3[j], m, 64);
            ac4[j] += __shfl_xor(ac4[j], m, 64);
        }
    }

    if (qtr == 0) {
        float i0 = (den0 > 0.f) ? 1.f / den0 : 0.f;
        float i1 = (den1 > 0.f) ? 1.f / den1 : 0.f;
        float i2 = (den2 > 0.f) ? 1.f / den2 : 0.f;
        float i3 = (den3 > 0.f) ? 1.f / den3 : 0.f;
        float i4 = (den4 > 0.f) ? 1.f / den4 : 0.f;
        f32x4 sv = *reinterpret_cast<const f32x4*>(s + (size_t)wid * OUT_CH + 4 * lr);
        f32x4 r;
        #pragma unroll
        for (int j = 0; j < 4; j++) {
            float sum = ac0[j]*i0 + ac1[j]*i1 + ac2[j]*i2 + ac3[j]*i3 + ac4[j]*i4;
            r[j] = fmaxf(sum * 0.2f + sv[j], 0.f);
        }
        *reinterpret_cast<f32x4*>(out + (size_t)wid * OUT_CH + 4 * lr) = r;
    }
}

// ---------------- launch ----------------

extern "C" void kernel_launch(void* const* d_in, const int* in_sizes, int n_in,
                              void* d_out, int out_size, void* d_ws, size_t ws_size,
                              hipStream_t stream)
{
    const float* x   = (const float*)d_in[0];
    const int*   ei  = (const int*)d_in[1];
    const int*   src = ei;
    const int*   dst = ei + N_EDGES;
    const float* q1w = (const float*)d_in[2];  const float* q1b = (const float*)d_in[3];
    const float* k1w = (const float*)d_in[4];  const float* k1b = (const float*)d_in[5];
    const float* v1w = (const float*)d_in[6];  const float* v1b = (const float*)d_in[7];
    const float* s1w = (const float*)d_in[8];  const float* s1b = (const float*)d_in[9];
    const float* q2w = (const float*)d_in[10]; const float* q2b = (const float*)d_in[11];
    const float* k2w = (const float*)d_in[12]; const float* k2b = (const float*)d_in[13];
    const float* v2w = (const float*)d_in[14]; const float* v2b = (const float*)d_in[15];
    const float* s2w = (const float*)d_in[16]; const float* s2b = (const float*)d_in[17];

    char* ws = (char*)d_ws;
    size_t off = 0;
    auto alloc = [&](size_t bytes) -> void* {
        void* p = ws + off;
        off += (bytes + 255) & ~(size_t)255;
        return p;
    };
    u32*  qp   = (u32*) alloc((size_t)2 * NN64 * 4);
    bf16* q4   = (bf16*)alloc((size_t)NN64 * 2);
    u32*  kp   = (u32*) alloc((size_t)2 * NN64 * 4);
    bf16* k4   = (bf16*)alloc((size_t)NN64 * 2);
    u32*  vp   = (u32*) alloc((size_t)2 * NN64 * 4);
    bf16* v4   = (bf16*)alloc((size_t)NN64 * 2);
    float* sbuf = (float*)alloc((size_t)NN64 * 4);
    float* hbuf = (float*)alloc((size_t)NN64 * 4);
    bf16* pq1 = (bf16*)alloc(40960 * 2);
    bf16* pk1 = (bf16*)alloc(40960 * 2);
    bf16* pv1 = (bf16*)alloc(40960 * 2);
    bf16* ps1 = (bf16*)alloc(8192 * 2);
    bf16* pq2 = (bf16*)alloc(20480 * 2);
    bf16* pk2 = (bf16*)alloc(20480 * 2);
    bf16* pv2 = (bf16*)alloc(20480 * 2);
    bf16* ps2 = (bf16*)alloc(4096 * 2);
    int*  row_ptr = (int*)alloc((size_t)(N_NODES + 1) * 4);
    int*  cursor  = (int*)alloc((size_t)N_NODES * 4);
    int*  counts  = (int*)alloc((size_t)N_NODES * 4);
    int*  csr_src = (int*)alloc((size_t)N_EDGES * 4);

    // weight repack + CSR build (stateless per call)
    repack_weights<<<768, 256, 0, stream>>>(q1w, k1w, v1w, s1w, q2w, k2w, v2w, s2w,
                                            pq1, pk1, pv1, ps1, pq2, pk2, pv2, ps2);
    hipMemsetAsync(counts, 0, (size_t)N_NODES * 4, stream);
    hist_kernel<<<(N_EDGES + 255) / 256, 256, 0, stream>>>(dst, counts, N_EDGES);
    scan_kernel<<<1, 1024, 0, stream>>>(counts, row_ptr, cursor, N_NODES);
    scatter_kernel<<<(N_EDGES + 255) / 256, 256, 0, stream>>>(src, dst, cursor, csr_src, N_EDGES);

    dim3 gg((N_NODES + 63) / 64, 4);

    // layer 1
    gemm_fused<IN_CH><<<gg, 256, 0, stream>>>(x, N_NODES,
        pq1, pk1, pv1, ps1, q1b, k1b, v1b, s1b,
        qp, q4, kp, k4, vp, v4, sbuf);
    attn_kernel<<<(N_NODES + 3) / 4, 256, 0, stream>>>(
        qp, q4, kp, k4, vp, v4, sbuf, row_ptr, csr_src, hbuf, N_NODES);

    // layer 2
    gemm_fused<OUT_CH><<<gg, 256, 0, stream>>>(hbuf, N_NODES,
        pq2, pk2, pv2, ps2, q2b, k2b, v2b, s2b,
        qp, q4, kp, k4, vp, v4, sbuf);
    attn_kernel<<<(N_NODES + 3) / 4, 256, 0, stream>>>(
        qp, q4, kp, k4, vp, v4, sbuf, row_ptr, csr_src, (float*)d_out, N_NODES);
}